// Round 2
// baseline (250.242 us; speedup 1.0000x reference)
//
#include <hip/hip_runtime.h>
#include <hip/hip_bf16.h>

#define BB 16
#define LL 2048
#define DD 256
#define NN 16
#define RR 16
#define CH 32
#define LC (LL/CH)   /* 64 */

static __device__ __forceinline__ float bf2f(unsigned short u) {
    return __uint_as_float(((unsigned)u) << 16);
}
static __device__ __forceinline__ unsigned short f2bf(float f) {
    unsigned u = __float_as_uint(f);
    u += 0x7FFFu + ((u >> 16) & 1u);
    return (unsigned short)(u >> 16);
}

typedef __attribute__((ext_vector_type(8))) short bf16x8;
typedef __attribute__((ext_vector_type(4))) float f32x4;

// ---------------------------------------------------------------------------
// Kernel A: LayerNorm + x_proj (256->48) + dt_proj (16->256) + softplus
// one block per (b,l) row, 256 threads
// ---------------------------------------------------------------------------
__global__ __launch_bounds__(256) void k_ln_proj(
    const float* __restrict__ x,
    const float* __restrict__ ln_w,
    const float* __restrict__ ln_b,
    const float* __restrict__ xw,   // (256,48)
    const float* __restrict__ dtw,  // (16,256)
    const float* __restrict__ dtb,  // (256)
    unsigned short* __restrict__ xln,
    unsigned short* __restrict__ delta,
    float* __restrict__ Bv,
    float* __restrict__ Cv)
{
    const int row = blockIdx.x;
    const int t = threadIdx.x;
    const int wid = t >> 6, lane = t & 63;
    __shared__ float sxln[DD];
    __shared__ float red[256];
    __shared__ float sdt[16];
    __shared__ float s_sum[4], s_sq[4];

    float xv = x[(size_t)row*DD + t];
    float s = xv, q = xv*xv;
    #pragma unroll
    for (int o = 32; o > 0; o >>= 1) {
        s += __shfl_down(s, o);
        q += __shfl_down(q, o);
    }
    if (lane == 0) { s_sum[wid] = s; s_sq[wid] = q; }
    __syncthreads();
    float sum = s_sum[0]+s_sum[1]+s_sum[2]+s_sum[3];
    float sq  = s_sq[0]+s_sq[1]+s_sq[2]+s_sq[3];
    float mu  = sum * (1.0f/DD);
    float var = sq  * (1.0f/DD) - mu*mu;
    float rs  = rsqrtf(var + 1e-5f);
    float xn  = (xv - mu)*rs*ln_w[t] + ln_b[t];
    sxln[t] = xn;
    xln[(size_t)row*DD + t] = f2bf(xn);
    __syncthreads();

    // x_proj: 48 outputs, 4 partial K-slices
    const int j = t & 63, p = t >> 6;
    float part = 0.f;
    if (j < 48) {
        const int k0 = p*64;
        #pragma unroll 8
        for (int k = 0; k < 64; ++k)
            part += sxln[k0+k] * xw[(k0+k)*48 + j];
    }
    red[t] = part;
    __syncthreads();
    if (t < 48) {
        float v = red[t] + red[64+t] + red[128+t] + red[192+t];
        if (t < 16)      sdt[t] = v;
        else if (t < 32) Bv[(size_t)row*NN + (t-16)] = v;
        else             Cv[(size_t)row*NN + (t-32)] = v;
    }
    __syncthreads();

    // dt_proj + softplus
    float acc = dtb[t];
    #pragma unroll
    for (int jj = 0; jj < RR; ++jj)
        acc += sdt[jj] * dtw[jj*DD + t];
    float sp;
    if (acc > 15.f) sp = acc;
    else sp = 0.69314718f * log2f(1.f + exp2f(acc * 1.44269504f));
    delta[(size_t)row*DD + t] = f2bf(sp);
}

// ---------------------------------------------------------------------------
// Kernel B: scan pass 1 — per-chunk local state S and decay P = exp(A*sum dl)
// grid = B*CH blocks, 256 threads (one per d-channel)
// ---------------------------------------------------------------------------
__global__ __launch_bounds__(256) void k_scan1(
    const unsigned short* __restrict__ delta,
    const unsigned short* __restrict__ xln,
    const float* __restrict__ Bv,
    const float* __restrict__ A_log,
    float* __restrict__ S, float* __restrict__ P)
{
    const int blk = blockIdx.x;
    const int c = blk & (CH-1);
    const int b = blk >> 5;
    const int d = threadIdx.x;
    float al[NN];
    #pragma unroll
    for (int n = 0; n < NN; ++n)
        al[n] = -expf(A_log[d*NN + n]) * 1.44269504f;
    float h[NN];
    #pragma unroll
    for (int n = 0; n < NN; ++n) h[n] = 0.f;
    float dsum = 0.f;
    const int l0 = c * LC;
    for (int l = l0; l < l0 + LC; ++l) {
        const size_t base = (size_t)b*LL + l;
        float dl = bf2f(delta[base*DD + d]);
        float xl = bf2f(xln[base*DD + d]);
        const float* Bp = Bv + base*NN;
        float dx = dl * xl;
        dsum += dl;
        #pragma unroll
        for (int n = 0; n < NN; ++n) {
            float e = exp2f(al[n]*dl);
            h[n] = fmaf(e, h[n], dx * Bp[n]);
        }
    }
    const size_t o = (size_t)blk * NN * DD + d;
    #pragma unroll
    for (int n = 0; n < NN; ++n) {
        S[o + n*DD] = h[n];
        P[o + n*DD] = exp2f(al[n]*dsum);
    }
}

// ---------------------------------------------------------------------------
// Kernel C: scan pass 2 — combine-prologue then full scan producing g = gelu(y)
// ---------------------------------------------------------------------------
__global__ __launch_bounds__(256) void k_scan2(
    const unsigned short* __restrict__ delta,
    const unsigned short* __restrict__ xln,
    const float* __restrict__ Bv,
    const float* __restrict__ Cv,
    const float* __restrict__ A_log,
    const float* __restrict__ S,
    const float* __restrict__ P,
    const float* __restrict__ Dskip,
    unsigned short* __restrict__ g)
{
    const int blk = blockIdx.x;
    const int c = blk & (CH-1);
    const int b = blk >> 5;
    const int d = threadIdx.x;
    float al[NN];
    #pragma unroll
    for (int n = 0; n < NN; ++n)
        al[n] = -expf(A_log[d*NN + n]) * 1.44269504f;
    float h[NN];
    #pragma unroll
    for (int n = 0; n < NN; ++n) h[n] = 0.f;
    // combine: fold preceding chunks' (S,P) into the incoming state
    for (int j = 0; j < c; ++j) {
        const size_t o = ((size_t)(b*CH + j)) * NN * DD + d;
        #pragma unroll
        for (int n = 0; n < NN; ++n)
            h[n] = fmaf(P[o + n*DD], h[n], S[o + n*DD]);
    }
    const float dsk = Dskip[d];
    const int l0 = c * LC;
    for (int l = l0; l < l0 + LC; ++l) {
        const size_t base = (size_t)b*LL + l;
        float dl = bf2f(delta[base*DD + d]);
        float xl = bf2f(xln[base*DD + d]);
        const float* Bp = Bv + base*NN;
        const float* Cp = Cv + base*NN;
        float dx = dl * xl;
        float y = 0.f;
        #pragma unroll
        for (int n = 0; n < NN; ++n) {
            float e = exp2f(al[n]*dl);
            h[n] = fmaf(e, h[n], dx * Bp[n]);
            y = fmaf(h[n], Cp[n], y);
        }
        float v = y + xl * dsk;
        // gelu (tanh form; |err| < 1e-3, threshold is 0.25)
        float u  = 0.7978845608f * (v + 0.044715f*v*v*v);
        float t2 = exp2f(2.8853900818f * u);
        float th = 1.f - 2.f/(t2 + 1.f);
        float gv = 0.5f * v * (1.f + th);
        g[base*DD + d] = f2bf(gv);
    }
}

// ---------------------------------------------------------------------------
// Transpose glu_w (256x512 fp32) -> Wt (512x256 bf16)
// ---------------------------------------------------------------------------
__global__ __launch_bounds__(256) void k_transpose(
    const float* __restrict__ W, unsigned short* __restrict__ Wt)
{
    __shared__ unsigned short s[32][33];
    const int bx = blockIdx.x; // n tile (16)
    const int by = blockIdx.y; // k tile (8)
    const int t = threadIdx.x;
    const int r = t >> 5, cc = t & 31;
    #pragma unroll
    for (int i = 0; i < 4; ++i)
        s[r + 8*i][cc] = f2bf(W[(size_t)(by*32 + r + 8*i)*512 + bx*32 + cc]);
    __syncthreads();
    #pragma unroll
    for (int i = 0; i < 4; ++i)
        Wt[(size_t)(bx*32 + r + 8*i)*256 + by*32 + cc] = s[cc][r + 8*i];
}

// ---------------------------------------------------------------------------
// Kernel E: GLU GEMM (32768x256 @ 256x512) + bias + sigmoid gate + skip
// block: 256 thr (4 waves), tile 64(M) x 64(N-pair: cols n0..n0+64 of both halves)
// ---------------------------------------------------------------------------
__global__ __launch_bounds__(256) void k_glu(
    const unsigned short* __restrict__ g,
    const unsigned short* __restrict__ Wt,
    const float* __restrict__ gb,
    const float* __restrict__ x,
    float* __restrict__ out)
{
    __shared__ unsigned short As[64][40];
    __shared__ unsigned short Bl[64][40];
    __shared__ unsigned short Bh[64][40];
    const int n0 = blockIdx.x * 64;
    const int m0 = blockIdx.y * 64;
    const int t = threadIdx.x;
    const int w = t >> 6, lane = t & 63;
    const int r = t >> 2, q = t & 3;
    const int cl = lane & 15, rq = lane >> 4;
    f32x4 accL[4], accH[4];
    const f32x4 zz = {0.f, 0.f, 0.f, 0.f};
    #pragma unroll
    for (int nf = 0; nf < 4; ++nf) { accL[nf] = zz; accH[nf] = zz; }

    for (int k0 = 0; k0 < 256; k0 += 32) {
        *(bf16x8*)(&As[r][q*8]) = *(const bf16x8*)(&g [(size_t)(m0+r)*DD + k0 + q*8]);
        *(bf16x8*)(&Bl[r][q*8]) = *(const bf16x8*)(&Wt[(size_t)(n0+r)*DD + k0 + q*8]);
        *(bf16x8*)(&Bh[r][q*8]) = *(const bf16x8*)(&Wt[(size_t)(n0+256+r)*DD + k0 + q*8]);
        __syncthreads();
        bf16x8 a = *(const bf16x8*)(&As[w*16 + cl][rq*8]);
        #pragma unroll
        for (int nf = 0; nf < 4; ++nf) {
            bf16x8 bl = *(const bf16x8*)(&Bl[nf*16 + cl][rq*8]);
            bf16x8 bh = *(const bf16x8*)(&Bh[nf*16 + cl][rq*8]);
            accL[nf] = __builtin_amdgcn_mfma_f32_16x16x32_bf16(a, bl, accL[nf], 0, 0, 0);
            accH[nf] = __builtin_amdgcn_mfma_f32_16x16x32_bf16(a, bh, accH[nf], 0, 0, 0);
        }
        __syncthreads();
    }
    #pragma unroll
    for (int nf = 0; nf < 4; ++nf) {
        const int j = n0 + nf*16 + cl;
        const float bL = gb[j];
        const float bH = gb[j + 256];
        #pragma unroll
        for (int rr = 0; rr < 4; ++rr) {
            const int m = m0 + w*16 + rq*4 + rr;
            float lo = accL[nf][rr] + bL;
            float hi = accH[nf][rr] + bH;
            float sg = 1.f / (1.f + exp2f(-1.44269504f * hi));
            out[(size_t)m*DD + j] = lo * sg + x[(size_t)m*DD + j];
        }
    }
}

extern "C" void kernel_launch(void* const* d_in, const int* in_sizes, int n_in,
                              void* d_out, int out_size, void* d_ws, size_t ws_size,
                              hipStream_t stream)
{
    const float* x    = (const float*)d_in[0];
    const float* ln_w = (const float*)d_in[1];
    const float* ln_b = (const float*)d_in[2];
    const float* xpw  = (const float*)d_in[3];
    const float* dtw  = (const float*)d_in[4];
    const float* dtb  = (const float*)d_in[5];
    const float* alog = (const float*)d_in[6];
    const float* dsk  = (const float*)d_in[7];
    const float* gw   = (const float*)d_in[8];
    const float* gb   = (const float*)d_in[9];
    float* out = (float*)d_out;

    char* ws = (char*)d_ws;
    size_t off = 0;
    auto alloc = [&](size_t bytes) {
        char* p = ws + off; off += (bytes + 255) & ~(size_t)255; return p;
    };
    unsigned short* xln   = (unsigned short*)alloc((size_t)BB*LL*DD*2);
    unsigned short* delta = (unsigned short*)alloc((size_t)BB*LL*DD*2);
    float*          Bvp   = (float*)         alloc((size_t)BB*LL*NN*4);
    float*          Cvp   = (float*)         alloc((size_t)BB*LL*NN*4);
    float*          S     = (float*)         alloc((size_t)BB*CH*NN*DD*4);
    float*          P     = (float*)         alloc((size_t)BB*CH*NN*DD*4);
    unsigned short* g     = (unsigned short*)alloc((size_t)BB*LL*DD*2);
    unsigned short* Wt    = (unsigned short*)alloc((size_t)512*256*2);

    k_ln_proj<<<BB*LL, 256, 0, stream>>>(x, ln_w, ln_b, xpw, dtw, dtb, xln, delta, Bvp, Cvp);
    k_transpose<<<dim3(16, 8), 256, 0, stream>>>(gw, Wt);
    k_scan1<<<BB*CH, 256, 0, stream>>>(delta, xln, Bvp, alog, S, P);
    k_scan2<<<BB*CH, 256, 0, stream>>>(delta, xln, Bvp, Cvp, alog, S, P, dsk, g);
    k_glu<<<dim3(4, 512), 256, 0, stream>>>(g, Wt, gb, x, out);
}

// Round 3
// 221.365 us; speedup vs baseline: 1.1305x; 1.1305x over previous
//
#include <hip/hip_runtime.h>
#include <hip/hip_bf16.h>

#define BB 16
#define LL 2048
#define DD 256
#define NN 16
#define RR 16
#define CH 64
#define LC (LL/CH)   /* 32 */

static __device__ __forceinline__ float bf2f(unsigned short u) {
    return __uint_as_float(((unsigned)u) << 16);
}
static __device__ __forceinline__ unsigned short f2bf(float f) {
    unsigned u = __float_as_uint(f);
    u += 0x7FFFu + ((u >> 16) & 1u);
    return (unsigned short)(u >> 16);
}

typedef __attribute__((ext_vector_type(8))) short bf16x8;
typedef __attribute__((ext_vector_type(4))) float f32x4;

// ---------------------------------------------------------------------------
// prep: Wxt[n][k] = xw[k][n] (bf16, n padded 48->64 with zeros). grid 16x256
// ---------------------------------------------------------------------------
__global__ __launch_bounds__(256) void k_prep_wx(
    const float* __restrict__ xw, unsigned short* __restrict__ Wxt)
{
    const int idx = blockIdx.x * 256 + threadIdx.x;   // 0..4095
    const int n  = idx >> 6;
    const int k0 = (idx & 63) * 4;
    #pragma unroll
    for (int i = 0; i < 4; ++i) {
        float v = (n < 48) ? xw[(size_t)(k0 + i) * 48 + n] : 0.f;
        Wxt[(size_t)n * DD + k0 + i] = f2bf(v);
    }
}

// ---------------------------------------------------------------------------
// Transpose glu_w (256x512 fp32) -> Wt (512x256 bf16)
// ---------------------------------------------------------------------------
__global__ __launch_bounds__(256) void k_transpose(
    const float* __restrict__ W, unsigned short* __restrict__ Wt)
{
    __shared__ unsigned short s[32][33];
    const int bx = blockIdx.x; // n tile (16)
    const int by = blockIdx.y; // k tile (8)
    const int t = threadIdx.x;
    const int r = t >> 5, cc = t & 31;
    #pragma unroll
    for (int i = 0; i < 4; ++i)
        s[r + 8*i][cc] = f2bf(W[(size_t)(by*32 + r + 8*i)*512 + bx*32 + cc]);
    __syncthreads();
    #pragma unroll
    for (int i = 0; i < 4; ++i)
        Wt[(size_t)(bx*32 + r + 8*i)*256 + by*32 + cc] = s[cc][r + 8*i];
}

// ---------------------------------------------------------------------------
// Kernel A (fused): LN (reg+shuffle) + x_proj via MFMA + dt_proj VALU + softplus
// 32 rows/block, 1024 blocks, 256 threads (4 waves)
// ---------------------------------------------------------------------------
__global__ __launch_bounds__(256) void k_ln_fused(
    const float* __restrict__ x,
    const float* __restrict__ ln_w,
    const float* __restrict__ ln_b,
    const unsigned short* __restrict__ Wxt,  // 64x256 bf16
    const float* __restrict__ dtw,           // 16x256
    const float* __restrict__ dtb,           // 256
    unsigned short* __restrict__ xln,
    unsigned short* __restrict__ delta,
    float* __restrict__ Bv,
    float* __restrict__ Cv)
{
    const int t = threadIdx.x;
    const int m0 = blockIdx.x * 32;
    const int row = t >> 3, seg = t & 7;
    const int grow = m0 + row;
    const int c0 = seg * 32;

    __shared__ unsigned short As[32][264];
    __shared__ unsigned short Bs[64][264];
    __shared__ float sdt[32][20];

    // ---- load x segment (32 floats) into registers
    float v[32];
    {
        const float* xp = x + (size_t)grow * DD + c0;
        #pragma unroll
        for (int i = 0; i < 8; ++i)
            *(float4*)&v[i*4] = *(const float4*)(xp + i*4);
    }
    // ---- LN stats: intra-thread + 8-lane shuffle reduce
    float s = 0.f, q = 0.f;
    #pragma unroll
    for (int i = 0; i < 32; ++i) { s += v[i]; q = fmaf(v[i], v[i], q); }
    #pragma unroll
    for (int o = 1; o < 8; o <<= 1) {
        s += __shfl_xor(s, o);
        q += __shfl_xor(q, o);
    }
    const float mu = s * (1.f/DD);
    const float rs = rsqrtf(q * (1.f/DD) - mu*mu + 1e-5f);
    // ---- normalize, cast, write global + LDS A-tile
    unsigned short o16[32];
    #pragma unroll
    for (int i = 0; i < 8; ++i) {
        const float4 wv = *(const float4*)(ln_w + c0 + i*4);
        const float4 bv = *(const float4*)(ln_b + c0 + i*4);
        o16[i*4+0] = f2bf((v[i*4+0]-mu)*rs*wv.x + bv.x);
        o16[i*4+1] = f2bf((v[i*4+1]-mu)*rs*wv.y + bv.y);
        o16[i*4+2] = f2bf((v[i*4+2]-mu)*rs*wv.z + bv.z);
        o16[i*4+3] = f2bf((v[i*4+3]-mu)*rs*wv.w + bv.w);
    }
    #pragma unroll
    for (int i = 0; i < 4; ++i) {
        *(bf16x8*)&xln[(size_t)grow*DD + c0 + i*8] = *(bf16x8*)&o16[i*8];
        *(bf16x8*)&As[row][c0 + i*8]               = *(bf16x8*)&o16[i*8];
    }
    // ---- stage Wxt into LDS B-tile (64x256 bf16)
    {
        const int rB = t >> 2, cB = (t & 3) * 64;
        #pragma unroll
        for (int i = 0; i < 8; ++i)
            *(bf16x8*)&Bs[rB][cB + i*8] =
                *(const bf16x8*)&Wxt[(size_t)rB*DD + cB + i*8];
    }
    __syncthreads();

    // ---- x_proj MFMA: (32x256)@(256x64->48)
    const int w = t >> 6, lane = t & 63;
    const int cl = lane & 15, rq = lane >> 4;
    const int mh = (w & 1) * 16;
    const int nh = (w >> 1) * 32;
    f32x4 acc0 = {0.f,0.f,0.f,0.f}, acc1 = {0.f,0.f,0.f,0.f};
    #pragma unroll
    for (int k0 = 0; k0 < 256; k0 += 32) {
        const bf16x8 a  = *(const bf16x8*)&As[mh + cl][k0 + rq*8];
        const bf16x8 b0 = *(const bf16x8*)&Bs[nh + cl][k0 + rq*8];
        acc0 = __builtin_amdgcn_mfma_f32_16x16x32_bf16(a, b0, acc0, 0, 0, 0);
        if (w < 2) {
            const bf16x8 b1 = *(const bf16x8*)&Bs[nh + 16 + cl][k0 + rq*8];
            acc1 = __builtin_amdgcn_mfma_f32_16x16x32_bf16(a, b1, acc1, 0, 0, 0);
        }
    }
    if (w < 2) {   // cols 0..15 -> dt (LDS), cols 16..31 -> Bv
        #pragma unroll
        for (int r = 0; r < 4; ++r) {
            sdt[mh + rq*4 + r][cl] = acc0[r];
            Bv[(size_t)(m0 + mh + rq*4 + r)*NN + cl] = acc1[r];
        }
    } else {       // cols 32..47 -> Cv
        #pragma unroll
        for (int r = 0; r < 4; ++r)
            Cv[(size_t)(m0 + mh + rq*4 + r)*NN + cl] = acc0[r];
    }
    __syncthreads();

    // ---- dt_proj (K=16) + softplus, float4-vectorized
    float dt[16];
    #pragma unroll
    for (int j = 0; j < 16; ++j) dt[j] = sdt[row][j];
    unsigned short d16[32];
    #pragma unroll
    for (int i = 0; i < 8; ++i) {
        const int c = c0 + i*4;
        float4 a4 = *(const float4*)(dtb + c);
        #pragma unroll
        for (int j = 0; j < 16; ++j) {
            const float4 w4 = *(const float4*)(dtw + j*DD + c);
            a4.x = fmaf(dt[j], w4.x, a4.x);
            a4.y = fmaf(dt[j], w4.y, a4.y);
            a4.z = fmaf(dt[j], w4.z, a4.z);
            a4.w = fmaf(dt[j], w4.w, a4.w);
        }
        #pragma unroll
        for (int jj = 0; jj < 4; ++jj) {
            const float ac = (&a4.x)[jj];
            const float sp = (ac > 15.f) ? ac
                : 0.69314718f * log2f(1.f + exp2f(ac * 1.44269504f));
            d16[i*4 + jj] = f2bf(sp);
        }
    }
    #pragma unroll
    for (int i = 0; i < 4; ++i)
        *(bf16x8*)&delta[(size_t)grow*DD + c0 + i*8] = *(bf16x8*)&d16[i*8];
}

// ---------------------------------------------------------------------------
// scan pass 1 — per-chunk local state S and delta-sum. grid B*CH, 256 thr
// ---------------------------------------------------------------------------
__global__ __launch_bounds__(256) void k_scan1(
    const unsigned short* __restrict__ delta,
    const unsigned short* __restrict__ xln,
    const float* __restrict__ Bv,
    const float* __restrict__ A_log,
    float* __restrict__ S, float* __restrict__ Dsum)
{
    const int blk = blockIdx.x;
    const int c = blk & (CH-1);
    const int b = blk >> 6;
    const int d = threadIdx.x;
    float al[NN];
    #pragma unroll
    for (int n = 0; n < NN; ++n)
        al[n] = -expf(A_log[d*NN + n]) * 1.44269504f;
    float h[NN];
    #pragma unroll
    for (int n = 0; n < NN; ++n) h[n] = 0.f;
    float dsum = 0.f;
    const int l0 = c * LC;
    for (int l = l0; l < l0 + LC; ++l) {
        const size_t base = (size_t)b*LL + l;
        const float dl = bf2f(delta[base*DD + d]);
        const float xl = bf2f(xln[base*DD + d]);
        const float* Bp = Bv + base*NN;
        const float dx = dl * xl;
        dsum += dl;
        #pragma unroll
        for (int n = 0; n < NN; ++n) {
            const float e = exp2f(al[n]*dl);
            h[n] = fmaf(e, h[n], dx * Bp[n]);
        }
    }
    const size_t o = (size_t)blk * NN * DD + d;
    #pragma unroll
    for (int n = 0; n < NN; ++n) S[o + n*DD] = h[n];
    Dsum[(size_t)blk*DD + d] = dsum;
}

// ---------------------------------------------------------------------------
// combine: sequential fold over chunks -> per-chunk incoming state Hin
// grid 256 blocks x 256 thr: one thread per (b, n, d)
// ---------------------------------------------------------------------------
__global__ __launch_bounds__(256) void k_combine(
    const float* __restrict__ S, const float* __restrict__ Dsum,
    const float* __restrict__ A_log, float* __restrict__ Hin)
{
    const int idx = blockIdx.x * 256 + threadIdx.x;
    const int d = idx & 255;
    const int n = (idx >> 8) & 15;
    const int b = idx >> 12;
    const float al = -expf(A_log[d*NN + n]) * 1.44269504f;
    float h = 0.f;
    for (int c = 0; c < CH; ++c) {
        const size_t blk = (size_t)b*CH + c;
        const size_t o = blk*NN*DD + (size_t)n*DD + d;
        Hin[o] = h;
        h = fmaf(exp2f(al * Dsum[blk*DD + d]), h, S[o]);
    }
}

// ---------------------------------------------------------------------------
// scan pass 2 — start from Hin, full scan producing g = gelu(y)  (g aliases delta)
// ---------------------------------------------------------------------------
__global__ __launch_bounds__(256) void k_scan2(
    const unsigned short* __restrict__ delta,
    const unsigned short* __restrict__ xln,
    const float* __restrict__ Bv,
    const float* __restrict__ Cv,
    const float* __restrict__ A_log,
    const float* __restrict__ Hin,
    const float* __restrict__ Dskip,
    unsigned short* __restrict__ g)
{
    const int blk = blockIdx.x;
    const int c = blk & (CH-1);
    const int b = blk >> 6;
    const int d = threadIdx.x;
    float al[NN];
    #pragma unroll
    for (int n = 0; n < NN; ++n)
        al[n] = -expf(A_log[d*NN + n]) * 1.44269504f;
    float h[NN];
    const size_t ob = (size_t)blk * NN * DD + d;
    #pragma unroll
    for (int n = 0; n < NN; ++n) h[n] = Hin[ob + n*DD];
    const float dsk = Dskip[d];
    const int l0 = c * LC;
    for (int l = l0; l < l0 + LC; ++l) {
        const size_t base = (size_t)b*LL + l;
        const float dl = bf2f(delta[base*DD + d]);
        const float xl = bf2f(xln[base*DD + d]);
        const float* Bp = Bv + base*NN;
        const float* Cp = Cv + base*NN;
        const float dx = dl * xl;
        float y = 0.f;
        #pragma unroll
        for (int n = 0; n < NN; ++n) {
            const float e = exp2f(al[n]*dl);
            h[n] = fmaf(e, h[n], dx * Bp[n]);
            y = fmaf(h[n], Cp[n], y);
        }
        const float vv = y + xl * dsk;
        // gelu (tanh form)
        const float u  = 0.7978845608f * (vv + 0.044715f*vv*vv*vv);
        const float t2 = exp2f(2.8853900818f * u);
        const float th = 1.f - 2.f/(t2 + 1.f);
        g[base*DD + d] = f2bf(0.5f * vv * (1.f + th));
    }
}

// ---------------------------------------------------------------------------
// GLU GEMM (32768x256 @ 256x512) + bias + sigmoid gate + skip
// ---------------------------------------------------------------------------
__global__ __launch_bounds__(256) void k_glu(
    const unsigned short* __restrict__ g,
    const unsigned short* __restrict__ Wt,
    const float* __restrict__ gb,
    const float* __restrict__ x,
    float* __restrict__ out)
{
    __shared__ unsigned short As[64][40];
    __shared__ unsigned short Bl[64][40];
    __shared__ unsigned short Bh[64][40];
    const int n0 = blockIdx.x * 64;
    const int m0 = blockIdx.y * 64;
    const int t = threadIdx.x;
    const int w = t >> 6, lane = t & 63;
    const int r = t >> 2, q = t & 3;
    const int cl = lane & 15, rq = lane >> 4;
    f32x4 accL[4], accH[4];
    const f32x4 zz = {0.f, 0.f, 0.f, 0.f};
    #pragma unroll
    for (int nf = 0; nf < 4; ++nf) { accL[nf] = zz; accH[nf] = zz; }

    for (int k0 = 0; k0 < 256; k0 += 32) {
        *(bf16x8*)(&As[r][q*8]) = *(const bf16x8*)(&g [(size_t)(m0+r)*DD + k0 + q*8]);
        *(bf16x8*)(&Bl[r][q*8]) = *(const bf16x8*)(&Wt[(size_t)(n0+r)*DD + k0 + q*8]);
        *(bf16x8*)(&Bh[r][q*8]) = *(const bf16x8*)(&Wt[(size_t)(n0+256+r)*DD + k0 + q*8]);
        __syncthreads();
        const bf16x8 a = *(const bf16x8*)(&As[w*16 + cl][rq*8]);
        #pragma unroll
        for (int nf = 0; nf < 4; ++nf) {
            const bf16x8 bl = *(const bf16x8*)(&Bl[nf*16 + cl][rq*8]);
            const bf16x8 bh = *(const bf16x8*)(&Bh[nf*16 + cl][rq*8]);
            accL[nf] = __builtin_amdgcn_mfma_f32_16x16x32_bf16(a, bl, accL[nf], 0, 0, 0);
            accH[nf] = __builtin_amdgcn_mfma_f32_16x16x32_bf16(a, bh, accH[nf], 0, 0, 0);
        }
        __syncthreads();
    }
    #pragma unroll
    for (int nf = 0; nf < 4; ++nf) {
        const int j = n0 + nf*16 + cl;
        const float bL = gb[j];
        const float bH = gb[j + 256];
        #pragma unroll
        for (int rr = 0; rr < 4; ++rr) {
            const int m = m0 + w*16 + rq*4 + rr;
            const float lo = accL[nf][rr] + bL;
            const float hi = accH[nf][rr] + bH;
            const float sg = 1.f / (1.f + exp2f(-1.44269504f * hi));
            out[(size_t)m*DD + j] = lo * sg + x[(size_t)m*DD + j];
        }
    }
}

extern "C" void kernel_launch(void* const* d_in, const int* in_sizes, int n_in,
                              void* d_out, int out_size, void* d_ws, size_t ws_size,
                              hipStream_t stream)
{
    const float* x    = (const float*)d_in[0];
    const float* ln_w = (const float*)d_in[1];
    const float* ln_b = (const float*)d_in[2];
    const float* xpw  = (const float*)d_in[3];
    const float* dtw  = (const float*)d_in[4];
    const float* dtb  = (const float*)d_in[5];
    const float* alog = (const float*)d_in[6];
    const float* dsk  = (const float*)d_in[7];
    const float* gw   = (const float*)d_in[8];
    const float* gb   = (const float*)d_in[9];
    float* out = (float*)d_out;

    char* ws = (char*)d_ws;
    size_t off = 0;
    auto alloc = [&](size_t bytes) {
        char* p = ws + off; off += (bytes + 255) & ~(size_t)255; return p;
    };
    unsigned short* xln   = (unsigned short*)alloc((size_t)BB*LL*DD*2);
    unsigned short* delta = (unsigned short*)alloc((size_t)BB*LL*DD*2);
    float*          Bvp   = (float*)         alloc((size_t)BB*LL*NN*4);
    float*          Cvp   = (float*)         alloc((size_t)BB*LL*NN*4);
    float*          S     = (float*)         alloc((size_t)BB*CH*NN*DD*4);
    float*          Dsum  = (float*)         alloc((size_t)BB*CH*DD*4);
    float*          Hin   = (float*)         alloc((size_t)BB*CH*NN*DD*4);
    unsigned short* Wt    = (unsigned short*)alloc((size_t)512*256*2);
    unsigned short* Wxt   = (unsigned short*)alloc((size_t)64*256*2);
    unsigned short* g     = delta;   // alias: scan2 overwrites delta in place

    k_prep_wx<<<16, 256, 0, stream>>>(xpw, Wxt);
    k_transpose<<<dim3(16, 8), 256, 0, stream>>>(gw, Wt);
    k_ln_fused<<<1024, 256, 0, stream>>>(x, ln_w, ln_b, Wxt, dtw, dtb, xln, delta, Bvp, Cvp);
    k_scan1<<<BB*CH, 256, 0, stream>>>(delta, xln, Bvp, alog, S, Dsum);
    k_combine<<<256, 256, 0, stream>>>(S, Dsum, alog, Hin);
    k_scan2<<<BB*CH, 256, 0, stream>>>(delta, xln, Bvp, Cvp, alog, Hin, dsk, g);
    k_glu<<<dim3(4, 512), 256, 0, stream>>>(g, Wt, gb, x, out);
}

// Round 4
// 176.919 us; speedup vs baseline: 1.4144x; 1.2512x over previous
//
#include <hip/hip_runtime.h>
#include <hip/hip_bf16.h>

#define BB 16
#define LL 2048
#define DD 256
#define NN 16
#define RR 16
#define CH 64
#define LC (LL/CH)   /* 32 */

static __device__ __forceinline__ float bf2f(unsigned short u) {
    return __uint_as_float(((unsigned)u) << 16);
}
static __device__ __forceinline__ unsigned short f2bf(float f) {
    unsigned u = __float_as_uint(f);
    u += 0x7FFFu + ((u >> 16) & 1u);
    return (unsigned short)(u >> 16);
}

typedef __attribute__((ext_vector_type(8))) short bf16x8;
typedef __attribute__((ext_vector_type(4))) float f32x4;

// e[n] = E^(n+1), depth-4 product tree (full-rate VALU instead of trans pipe)
static __device__ __forceinline__ void pow_tree(float E, float* e) {
    e[0] = E;
    e[1] = E * E;
    e[2] = e[1] * E;
    e[3] = e[1] * e[1];
    e[4] = e[3] * e[0];  e[5] = e[3] * e[1];  e[6] = e[3] * e[2];  e[7] = e[3] * e[3];
    e[8] = e[7] * e[0];  e[9] = e[7] * e[1];  e[10] = e[7] * e[2]; e[11] = e[7] * e[3];
    e[12] = e[7] * e[4]; e[13] = e[7] * e[5]; e[14] = e[7] * e[6]; e[15] = e[7] * e[7];
}

// ---------------------------------------------------------------------------
// prep: Wxt[n][k] = xw[k][n] (bf16, n padded 48->64 with zeros). grid 16x256
// ---------------------------------------------------------------------------
__global__ __launch_bounds__(256) void k_prep_wx(
    const float* __restrict__ xw, unsigned short* __restrict__ Wxt)
{
    const int idx = blockIdx.x * 256 + threadIdx.x;   // 0..4095
    const int n  = idx >> 6;
    const int k0 = (idx & 63) * 4;
    #pragma unroll
    for (int i = 0; i < 4; ++i) {
        float v = (n < 48) ? xw[(size_t)(k0 + i) * 48 + n] : 0.f;
        Wxt[(size_t)n * DD + k0 + i] = f2bf(v);
    }
}

// ---------------------------------------------------------------------------
// Transpose glu_w (256x512 fp32) -> Wt (512x256 bf16)
// ---------------------------------------------------------------------------
__global__ __launch_bounds__(256) void k_transpose(
    const float* __restrict__ W, unsigned short* __restrict__ Wt)
{
    __shared__ unsigned short s[32][33];
    const int bx = blockIdx.x; // n tile (16)
    const int by = blockIdx.y; // k tile (8)
    const int t = threadIdx.x;
    const int r = t >> 5, cc = t & 31;
    #pragma unroll
    for (int i = 0; i < 4; ++i)
        s[r + 8*i][cc] = f2bf(W[(size_t)(by*32 + r + 8*i)*512 + bx*32 + cc]);
    __syncthreads();
    #pragma unroll
    for (int i = 0; i < 4; ++i)
        Wt[(size_t)(bx*32 + r + 8*i)*256 + by*32 + cc] = s[cc][r + 8*i];
}

// ---------------------------------------------------------------------------
// Kernel A (fused): LN (reg+shuffle) + x_proj MFMA (B direct from global)
// + dt_proj VALU + softplus. 32 rows/block, 1024 blocks, 256 threads.
// LDS ~19.5 KB -> 5 blocks/CU (VGPR-limited), vs 52 KB / 3 blocks before.
// ---------------------------------------------------------------------------
__global__ __launch_bounds__(256) void k_ln_fused(
    const float* __restrict__ x,
    const float* __restrict__ ln_w,
    const float* __restrict__ ln_b,
    const unsigned short* __restrict__ Wxt,  // 64x256 bf16
    const float* __restrict__ dtw,           // 16x256
    const float* __restrict__ dtb,           // 256
    unsigned short* __restrict__ xln,
    unsigned short* __restrict__ delta,
    float* __restrict__ Bv,
    float* __restrict__ Cv)
{
    const int t = threadIdx.x;
    const int m0 = blockIdx.x * 32;
    const int row = t >> 3, seg = t & 7;
    const int grow = m0 + row;
    const int c0 = seg * 32;

    __shared__ unsigned short As[32][264];
    __shared__ float sdt[32][20];

    // ---- load x segment (32 floats) into registers
    float v[32];
    {
        const float* xp = x + (size_t)grow * DD + c0;
        #pragma unroll
        for (int i = 0; i < 8; ++i)
            *(float4*)&v[i*4] = *(const float4*)(xp + i*4);
    }
    // ---- LN stats: intra-thread + 8-lane shuffle reduce
    float s = 0.f, q = 0.f;
    #pragma unroll
    for (int i = 0; i < 32; ++i) { s += v[i]; q = fmaf(v[i], v[i], q); }
    #pragma unroll
    for (int o = 1; o < 8; o <<= 1) {
        s += __shfl_xor(s, o);
        q += __shfl_xor(q, o);
    }
    const float mu = s * (1.f/DD);
    const float rs = rsqrtf(q * (1.f/DD) - mu*mu + 1e-5f);
    // ---- normalize, cast, write global + LDS A-tile
    unsigned short o16[32];
    #pragma unroll
    for (int i = 0; i < 8; ++i) {
        const float4 wv = *(const float4*)(ln_w + c0 + i*4);
        const float4 bv = *(const float4*)(ln_b + c0 + i*4);
        o16[i*4+0] = f2bf((v[i*4+0]-mu)*rs*wv.x + bv.x);
        o16[i*4+1] = f2bf((v[i*4+1]-mu)*rs*wv.y + bv.y);
        o16[i*4+2] = f2bf((v[i*4+2]-mu)*rs*wv.z + bv.z);
        o16[i*4+3] = f2bf((v[i*4+3]-mu)*rs*wv.w + bv.w);
    }
    #pragma unroll
    for (int i = 0; i < 4; ++i) {
        *(bf16x8*)&xln[(size_t)grow*DD + c0 + i*8] = *(bf16x8*)&o16[i*8];
        *(bf16x8*)&As[row][c0 + i*8]               = *(bf16x8*)&o16[i*8];
    }
    __syncthreads();

    // ---- x_proj MFMA: (32x256)@(256x48), B-fragments direct from global Wxt
    const int w = t >> 6, lane = t & 63;
    const int cl = lane & 15, rq = lane >> 4;
    const int mh = (w & 1) * 16;
    const int nh = (w >> 1) * 32;
    f32x4 acc0 = {0.f,0.f,0.f,0.f}, acc1 = {0.f,0.f,0.f,0.f};
    #pragma unroll
    for (int k0 = 0; k0 < 256; k0 += 32) {
        const bf16x8 a  = *(const bf16x8*)&As[mh + cl][k0 + rq*8];
        const bf16x8 b0 = *(const bf16x8*)&Wxt[(size_t)(nh + cl)*DD + k0 + rq*8];
        acc0 = __builtin_amdgcn_mfma_f32_16x16x32_bf16(a, b0, acc0, 0, 0, 0);
        if (w < 2) {
            const bf16x8 b1 = *(const bf16x8*)&Wxt[(size_t)(nh + 16 + cl)*DD + k0 + rq*8];
            acc1 = __builtin_amdgcn_mfma_f32_16x16x32_bf16(a, b1, acc1, 0, 0, 0);
        }
    }
    if (w < 2) {   // cols 0..15 -> dt (LDS), cols 16..31 -> Bv
        #pragma unroll
        for (int r = 0; r < 4; ++r) {
            sdt[mh + rq*4 + r][cl] = acc0[r];
            Bv[(size_t)(m0 + mh + rq*4 + r)*NN + cl] = acc1[r];
        }
    } else {       // cols 32..47 -> Cv
        #pragma unroll
        for (int r = 0; r < 4; ++r)
            Cv[(size_t)(m0 + mh + rq*4 + r)*NN + cl] = acc0[r];
    }
    __syncthreads();

    // ---- dt_proj (K=16) + softplus, float4-vectorized
    float dt[16];
    #pragma unroll
    for (int j = 0; j < 16; ++j) dt[j] = sdt[row][j];
    unsigned short d16[32];
    #pragma unroll
    for (int i = 0; i < 8; ++i) {
        const int c = c0 + i*4;
        float4 a4 = *(const float4*)(dtb + c);
        #pragma unroll
        for (int j = 0; j < 16; ++j) {
            const float4 w4 = *(const float4*)(dtw + j*DD + c);
            a4.x = fmaf(dt[j], w4.x, a4.x);
            a4.y = fmaf(dt[j], w4.y, a4.y);
            a4.z = fmaf(dt[j], w4.z, a4.z);
            a4.w = fmaf(dt[j], w4.w, a4.w);
        }
        #pragma unroll
        for (int jj = 0; jj < 4; ++jj) {
            const float ac = (&a4.x)[jj];
            const float sp = (ac > 15.f) ? ac
                : 0.69314718f * log2f(1.f + exp2f(ac * 1.44269504f));
            d16[i*4 + jj] = f2bf(sp);
        }
    }
    #pragma unroll
    for (int i = 0; i < 4; ++i)
        *(bf16x8*)&delta[(size_t)grow*DD + c0 + i*8] = *(bf16x8*)&d16[i*8];
}

// ---------------------------------------------------------------------------
// scan pass 1 — per-chunk local state S and delta-sum. grid B*CH, 256 thr
// ---------------------------------------------------------------------------
template<bool FAST>
__device__ __forceinline__ void scan1_impl(
    const unsigned short* __restrict__ delta,
    const unsigned short* __restrict__ xln,
    const float* __restrict__ Bv,
    const float* al, int b, int c, int d,
    float* h, float* dsum)
{
    const int l0 = c * LC;
    for (int l = l0; l < l0 + LC; ++l) {
        const size_t base = (size_t)b*LL + l;
        const float dl = bf2f(delta[base*DD + d]);
        const float xl = bf2f(xln[base*DD + d]);
        const float* Bp = Bv + base*NN;
        const float dx = dl * xl;
        *dsum += dl;
        float e[NN];
        if (FAST) pow_tree(exp2f(al[0]*dl), e);
        else {
            #pragma unroll
            for (int n = 0; n < NN; ++n) e[n] = exp2f(al[n]*dl);
        }
        #pragma unroll
        for (int n = 0; n < NN; ++n)
            h[n] = fmaf(e[n], h[n], dx * Bp[n]);
    }
}

__global__ __launch_bounds__(256) void k_scan1(
    const unsigned short* __restrict__ delta,
    const unsigned short* __restrict__ xln,
    const float* __restrict__ Bv,
    const float* __restrict__ A_log,
    float* __restrict__ S, float* __restrict__ Dsum)
{
    const int blk = blockIdx.x;
    const int c = blk & (CH-1);
    const int b = blk >> 6;
    const int d = threadIdx.x;
    float al[NN];
    bool fast = true;
    #pragma unroll
    for (int n = 0; n < NN; ++n) {
        al[n] = -expf(A_log[d*NN + n]) * 1.44269504f;
        fast = fast && (fabsf(al[n] - (n+1)*al[0]) <= 1e-3f*fabsf(al[n]) + 1e-6f);
    }
    float h[NN];
    #pragma unroll
    for (int n = 0; n < NN; ++n) h[n] = 0.f;
    float dsum = 0.f;
    if (fast) scan1_impl<true >(delta, xln, Bv, al, b, c, d, h, &dsum);
    else      scan1_impl<false>(delta, xln, Bv, al, b, c, d, h, &dsum);
    const size_t o = (size_t)blk * NN * DD + d;
    #pragma unroll
    for (int n = 0; n < NN; ++n) S[o + n*DD] = h[n];
    Dsum[(size_t)blk*DD + d] = dsum;
}

// ---------------------------------------------------------------------------
// combine: sequential fold over chunks -> per-chunk incoming state Hin
// grid 256 blocks x 256 thr: one thread per (b, n, d)
// ---------------------------------------------------------------------------
__global__ __launch_bounds__(256) void k_combine(
    const float* __restrict__ S, const float* __restrict__ Dsum,
    const float* __restrict__ A_log, float* __restrict__ Hin)
{
    const int idx = blockIdx.x * 256 + threadIdx.x;
    const int d = idx & 255;
    const int n = (idx >> 8) & 15;
    const int b = idx >> 12;
    const float al = -expf(A_log[d*NN + n]) * 1.44269504f;
    float h = 0.f;
    for (int c = 0; c < CH; ++c) {
        const size_t blk = (size_t)b*CH + c;
        const size_t o = blk*NN*DD + (size_t)n*DD + d;
        Hin[o] = h;
        h = fmaf(exp2f(al * Dsum[blk*DD + d]), h, S[o]);
    }
}

// ---------------------------------------------------------------------------
// scan pass 2 — start from Hin, full scan producing g = gelu(y)  (g aliases delta)
// ---------------------------------------------------------------------------
template<bool FAST>
__device__ __forceinline__ void scan2_impl(
    const unsigned short* __restrict__ delta,
    const unsigned short* __restrict__ xln,
    const float* __restrict__ Bv,
    const float* __restrict__ Cv,
    const float* al, int b, int c, int d,
    float* h, float dsk, unsigned short* __restrict__ g)
{
    const int l0 = c * LC;
    for (int l = l0; l < l0 + LC; ++l) {
        const size_t base = (size_t)b*LL + l;
        const float dl = bf2f(delta[base*DD + d]);
        const float xl = bf2f(xln[base*DD + d]);
        const float* Bp = Bv + base*NN;
        const float* Cp = Cv + base*NN;
        const float dx = dl * xl;
        float e[NN];
        if (FAST) pow_tree(exp2f(al[0]*dl), e);
        else {
            #pragma unroll
            for (int n = 0; n < NN; ++n) e[n] = exp2f(al[n]*dl);
        }
        float y = 0.f;
        #pragma unroll
        for (int n = 0; n < NN; ++n) {
            h[n] = fmaf(e[n], h[n], dx * Bp[n]);
            y = fmaf(h[n], Cp[n], y);
        }
        const float vv = y + xl * dsk;
        // gelu (tanh form)
        const float u  = 0.7978845608f * (vv + 0.044715f*vv*vv*vv);
        const float t2 = exp2f(2.8853900818f * u);
        const float th = 1.f - 2.f/(t2 + 1.f);
        g[base*DD + d] = f2bf(0.5f * vv * (1.f + th));
    }
}

__global__ __launch_bounds__(256) void k_scan2(
    const unsigned short* __restrict__ delta,
    const unsigned short* __restrict__ xln,
    const float* __restrict__ Bv,
    const float* __restrict__ Cv,
    const float* __restrict__ A_log,
    const float* __restrict__ Hin,
    const float* __restrict__ Dskip,
    unsigned short* __restrict__ g)
{
    const int blk = blockIdx.x;
    const int c = blk & (CH-1);
    const int b = blk >> 6;
    const int d = threadIdx.x;
    float al[NN];
    bool fast = true;
    #pragma unroll
    for (int n = 0; n < NN; ++n) {
        al[n] = -expf(A_log[d*NN + n]) * 1.44269504f;
        fast = fast && (fabsf(al[n] - (n+1)*al[0]) <= 1e-3f*fabsf(al[n]) + 1e-6f);
    }
    float h[NN];
    const size_t ob = (size_t)blk * NN * DD + d;
    #pragma unroll
    for (int n = 0; n < NN; ++n) h[n] = Hin[ob + n*DD];
    const float dsk = Dskip[d];
    if (fast) scan2_impl<true >(delta, xln, Bv, Cv, al, b, c, d, h, dsk, g);
    else      scan2_impl<false>(delta, xln, Bv, Cv, al, b, c, d, h, dsk, g);
}

// ---------------------------------------------------------------------------
// GLU GEMM (32768x256 @ 256x512) + bias + sigmoid gate + skip
// ---------------------------------------------------------------------------
__global__ __launch_bounds__(256) void k_glu(
    const unsigned short* __restrict__ g,
    const unsigned short* __restrict__ Wt,
    const float* __restrict__ gb,
    const float* __restrict__ x,
    float* __restrict__ out)
{
    __shared__ unsigned short As[64][40];
    __shared__ unsigned short Bl[64][40];
    __shared__ unsigned short Bh[64][40];
    const int n0 = blockIdx.x * 64;
    const int m0 = blockIdx.y * 64;
    const int t = threadIdx.x;
    const int w = t >> 6, lane = t & 63;
    const int r = t >> 2, q = t & 3;
    const int cl = lane & 15, rq = lane >> 4;
    f32x4 accL[4], accH[4];
    const f32x4 zz = {0.f, 0.f, 0.f, 0.f};
    #pragma unroll
    for (int nf = 0; nf < 4; ++nf) { accL[nf] = zz; accH[nf] = zz; }

    for (int k0 = 0; k0 < 256; k0 += 32) {
        *(bf16x8*)(&As[r][q*8]) = *(const bf16x8*)(&g [(size_t)(m0+r)*DD + k0 + q*8]);
        *(bf16x8*)(&Bl[r][q*8]) = *(const bf16x8*)(&Wt[(size_t)(n0+r)*DD + k0 + q*8]);
        *(bf16x8*)(&Bh[r][q*8]) = *(const bf16x8*)(&Wt[(size_t)(n0+256+r)*DD + k0 + q*8]);
        __syncthreads();
        const bf16x8 a = *(const bf16x8*)(&As[w*16 + cl][rq*8]);
        #pragma unroll
        for (int nf = 0; nf < 4; ++nf) {
            const bf16x8 bl = *(const bf16x8*)(&Bl[nf*16 + cl][rq*8]);
            const bf16x8 bh = *(const bf16x8*)(&Bh[nf*16 + cl][rq*8]);
            accL[nf] = __builtin_amdgcn_mfma_f32_16x16x32_bf16(a, bl, accL[nf], 0, 0, 0);
            accH[nf] = __builtin_amdgcn_mfma_f32_16x16x32_bf16(a, bh, accH[nf], 0, 0, 0);
        }
        __syncthreads();
    }
    #pragma unroll
    for (int nf = 0; nf < 4; ++nf) {
        const int j = n0 + nf*16 + cl;
        const float bL = gb[j];
        const float bH = gb[j + 256];
        #pragma unroll
        for (int rr = 0; rr < 4; ++rr) {
            const int m = m0 + w*16 + rq*4 + rr;
            const float lo = accL[nf][rr] + bL;
            const float hi = accH[nf][rr] + bH;
            const float sg = 1.f / (1.f + exp2f(-1.44269504f * hi));
            out[(size_t)m*DD + j] = lo * sg + x[(size_t)m*DD + j];
        }
    }
}

extern "C" void kernel_launch(void* const* d_in, const int* in_sizes, int n_in,
                              void* d_out, int out_size, void* d_ws, size_t ws_size,
                              hipStream_t stream)
{
    const float* x    = (const float*)d_in[0];
    const float* ln_w = (const float*)d_in[1];
    const float* ln_b = (const float*)d_in[2];
    const float* xpw  = (const float*)d_in[3];
    const float* dtw  = (const float*)d_in[4];
    const float* dtb  = (const float*)d_in[5];
    const float* alog = (const float*)d_in[6];
    const float* dsk  = (const float*)d_in[7];
    const float* gw   = (const float*)d_in[8];
    const float* gb   = (const float*)d_in[9];
    float* out = (float*)d_out;

    char* ws = (char*)d_ws;
    size_t off = 0;
    auto alloc = [&](size_t bytes) {
        char* p = ws + off; off += (bytes + 255) & ~(size_t)255; return p;
    };
    unsigned short* xln   = (unsigned short*)alloc((size_t)BB*LL*DD*2);
    unsigned short* delta = (unsigned short*)alloc((size_t)BB*LL*DD*2);
    float*          Bvp   = (float*)         alloc((size_t)BB*LL*NN*4);
    float*          Cvp   = (float*)         alloc((size_t)BB*LL*NN*4);
    float*          S     = (float*)         alloc((size_t)BB*CH*NN*DD*4);
    float*          Dsum  = (float*)         alloc((size_t)BB*CH*DD*4);
    float*          Hin   = (float*)         alloc((size_t)BB*CH*NN*DD*4);
    unsigned short* Wt    = (unsigned short*)alloc((size_t)512*256*2);
    unsigned short* Wxt   = (unsigned short*)alloc((size_t)64*256*2);
    unsigned short* g     = delta;   // alias: scan2 overwrites delta in place

    k_prep_wx<<<16, 256, 0, stream>>>(xpw, Wxt);
    k_transpose<<<dim3(16, 8), 256, 0, stream>>>(gw, Wt);
    k_ln_fused<<<1024, 256, 0, stream>>>(x, ln_w, ln_b, Wxt, dtw, dtb, xln, delta, Bvp, Cvp);
    k_scan1<<<BB*CH, 256, 0, stream>>>(delta, xln, Bvp, alog, S, Dsum);
    k_combine<<<256, 256, 0, stream>>>(S, Dsum, alog, Hin);
    k_scan2<<<BB*CH, 256, 0, stream>>>(delta, xln, Bvp, Cvp, alog, Hin, dsk, g);
    k_glu<<<dim3(4, 512), 256, 0, stream>>>(g, Wt, gb, x, out);
}

// Round 5
// 117.294 us; speedup vs baseline: 2.1335x; 1.5083x over previous
//
#include <hip/hip_runtime.h>
#include <hip/hip_bf16.h>

#define BB 16
#define LL 2048
#define DD 256
#define NN 16
#define RR 16
#define CH 64
#define LC (LL/CH)   /* 32 */

static __device__ __forceinline__ float bf2f(unsigned short u) {
    return __uint_as_float(((unsigned)u) << 16);
}
static __device__ __forceinline__ unsigned short f2bf(float f) {
    unsigned u = __float_as_uint(f);
    u += 0x7FFFu + ((u >> 16) & 1u);
    return (unsigned short)(u >> 16);
}

typedef __attribute__((ext_vector_type(8))) short bf16x8;
typedef __attribute__((ext_vector_type(4))) short bf16x4;
typedef __attribute__((ext_vector_type(4))) float f32x4;

// e[n] = E^(n+1), depth-4 product tree (full-rate VALU instead of trans pipe)
static __device__ __forceinline__ void pow_tree(float E, float* e) {
    e[0] = E;
    e[1] = E * E;
    e[2] = e[1] * E;
    e[3] = e[1] * e[1];
    e[4] = e[3] * e[0];  e[5] = e[3] * e[1];  e[6] = e[3] * e[2];  e[7] = e[3] * e[3];
    e[8] = e[7] * e[0];  e[9] = e[7] * e[1];  e[10] = e[7] * e[2]; e[11] = e[7] * e[3];
    e[12] = e[7] * e[4]; e[13] = e[7] * e[5]; e[14] = e[7] * e[6]; e[15] = e[7] * e[7];
}

// ---------------------------------------------------------------------------
// prep: Wxt[n][k] = xw[k][n] (bf16, n padded 48->64 with zeros). grid 16x256
// ---------------------------------------------------------------------------
__global__ __launch_bounds__(256) void k_prep_wx(
    const float* __restrict__ xw, unsigned short* __restrict__ Wxt)
{
    const int idx = blockIdx.x * 256 + threadIdx.x;   // 0..4095
    const int n  = idx >> 6;
    const int k0 = (idx & 63) * 4;
    #pragma unroll
    for (int i = 0; i < 4; ++i) {
        float v = (n < 48) ? xw[(size_t)(k0 + i) * 48 + n] : 0.f;
        Wxt[(size_t)n * DD + k0 + i] = f2bf(v);
    }
}

// ---------------------------------------------------------------------------
// Transpose glu_w (256x512 fp32) -> Wt (512x256 bf16)
// ---------------------------------------------------------------------------
__global__ __launch_bounds__(256) void k_transpose(
    const float* __restrict__ W, unsigned short* __restrict__ Wt)
{
    __shared__ unsigned short s[32][33];
    const int bx = blockIdx.x; // n tile (16)
    const int by = blockIdx.y; // k tile (8)
    const int t = threadIdx.x;
    const int r = t >> 5, cc = t & 31;
    #pragma unroll
    for (int i = 0; i < 4; ++i)
        s[r + 8*i][cc] = f2bf(W[(size_t)(by*32 + r + 8*i)*512 + bx*32 + cc]);
    __syncthreads();
    #pragma unroll
    for (int i = 0; i < 4; ++i)
        Wt[(size_t)(bx*32 + r + 8*i)*256 + by*32 + cc] = s[cc][r + 8*i];
}

// ---------------------------------------------------------------------------
// Kernel A (fused): LN + x_proj MFMA + dt_proj + softplus.
// 32 rows/block, 1024 blocks, 256 threads.
// Small operands (dtw/dtb/ln_w/ln_b) staged in LDS -> VMEM-issue cut ~4x.
// Per-thread column map c = i*32 + seg*4 + v: strided so all staged-LDS
// reads are bank-conflict-free (8 segs x 4-float stride covers 32 banks).
// ---------------------------------------------------------------------------
__global__ __launch_bounds__(256) void k_ln_fused(
    const float* __restrict__ x,
    const float* __restrict__ ln_w,
    const float* __restrict__ ln_b,
    const unsigned short* __restrict__ Wxt,  // 64x256 bf16
    const float* __restrict__ dtw,           // 16x256
    const float* __restrict__ dtb,           // 256
    unsigned short* __restrict__ xln,
    unsigned short* __restrict__ delta,
    float* __restrict__ Bv,
    float* __restrict__ Cv)
{
    const int t = threadIdx.x;
    const int m0 = blockIdx.x * 32;
    const int row = t >> 3, seg = t & 7;
    const int grow = m0 + row;

    __shared__ unsigned short As[32][264];
    __shared__ float sdt[32][20];
    __shared__ float sdtw[16*256];
    __shared__ float slnw[256], slnb[256], sdtb[256];

    // ---- stage small operands into LDS
    {
        const int tt = t & 63;
        if (t < 64)       *(float4*)&slnw[tt*4] = *(const float4*)&ln_w[tt*4];
        else if (t < 128) *(float4*)&slnb[tt*4] = *(const float4*)&ln_b[tt*4];
        else if (t < 192) *(float4*)&sdtb[tt*4] = *(const float4*)&dtb[tt*4];
        #pragma unroll
        for (int k = 0; k < 4; ++k)
            *(float4*)&sdtw[(k*256 + t)*4] = *(const float4*)&dtw[(k*256 + t)*4];
    }

    // ---- load x (strided map) into registers
    float v[32];
    #pragma unroll
    for (int i = 0; i < 8; ++i)
        *(float4*)&v[i*4] = *(const float4*)(x + (size_t)grow*DD + i*32 + seg*4);

    // ---- LN stats: intra-thread + 8-lane shuffle reduce
    float s = 0.f, q = 0.f;
    #pragma unroll
    for (int i = 0; i < 32; ++i) { s += v[i]; q = fmaf(v[i], v[i], q); }
    #pragma unroll
    for (int o = 1; o < 8; o <<= 1) {
        s += __shfl_xor(s, o);
        q += __shfl_xor(q, o);
    }
    const float mu = s * (1.f/DD);
    const float rs = rsqrtf(q * (1.f/DD) - mu*mu + 1e-5f);
    __syncthreads();   // staging complete

    // ---- normalize, cast, write global + LDS A-tile
    unsigned short o16[32];
    #pragma unroll
    for (int i = 0; i < 8; ++i) {
        const int c = i*32 + seg*4;
        const float4 wv = *(const float4*)&slnw[c];
        const float4 bv = *(const float4*)&slnb[c];
        o16[i*4+0] = f2bf((v[i*4+0]-mu)*rs*wv.x + bv.x);
        o16[i*4+1] = f2bf((v[i*4+1]-mu)*rs*wv.y + bv.y);
        o16[i*4+2] = f2bf((v[i*4+2]-mu)*rs*wv.z + bv.z);
        o16[i*4+3] = f2bf((v[i*4+3]-mu)*rs*wv.w + bv.w);
    }
    #pragma unroll
    for (int i = 0; i < 8; ++i) {
        const int c = i*32 + seg*4;
        *(bf16x4*)&xln[(size_t)grow*DD + c] = *(bf16x4*)&o16[i*4];
        *(bf16x4*)&As[row][c]               = *(bf16x4*)&o16[i*4];
    }
    __syncthreads();

    // ---- x_proj MFMA: (32x256)@(256x48), B-fragments direct from global Wxt
    const int w = t >> 6, lane = t & 63;
    const int cl = lane & 15, rq = lane >> 4;
    const int mh = (w & 1) * 16;
    const int nh = (w >> 1) * 32;
    f32x4 acc0 = {0.f,0.f,0.f,0.f}, acc1 = {0.f,0.f,0.f,0.f};
    #pragma unroll
    for (int k0 = 0; k0 < 256; k0 += 32) {
        const bf16x8 a  = *(const bf16x8*)&As[mh + cl][k0 + rq*8];
        const bf16x8 b0 = *(const bf16x8*)&Wxt[(size_t)(nh + cl)*DD + k0 + rq*8];
        acc0 = __builtin_amdgcn_mfma_f32_16x16x32_bf16(a, b0, acc0, 0, 0, 0);
        if (w < 2) {
            const bf16x8 b1 = *(const bf16x8*)&Wxt[(size_t)(nh + 16 + cl)*DD + k0 + rq*8];
            acc1 = __builtin_amdgcn_mfma_f32_16x16x32_bf16(a, b1, acc1, 0, 0, 0);
        }
    }
    if (w < 2) {   // cols 0..15 -> dt (LDS), cols 16..31 -> Bv
        #pragma unroll
        for (int r = 0; r < 4; ++r) {
            sdt[mh + rq*4 + r][cl] = acc0[r];
            Bv[(size_t)(m0 + mh + rq*4 + r)*NN + cl] = acc1[r];
        }
    } else {       // cols 32..47 -> Cv
        #pragma unroll
        for (int r = 0; r < 4; ++r)
            Cv[(size_t)(m0 + mh + rq*4 + r)*NN + cl] = acc0[r];
    }
    __syncthreads();

    // ---- dt_proj (K=16) + softplus, all operands from LDS
    float dt[16];
    #pragma unroll
    for (int j = 0; j < 16; ++j) dt[j] = sdt[row][j];
    #pragma unroll
    for (int i = 0; i < 8; ++i) {
        const int c = i*32 + seg*4;
        float4 a4 = *(const float4*)&sdtb[c];
        #pragma unroll
        for (int j = 0; j < 16; ++j) {
            const float4 w4 = *(const float4*)&sdtw[j*256 + c];
            a4.x = fmaf(dt[j], w4.x, a4.x);
            a4.y = fmaf(dt[j], w4.y, a4.y);
            a4.z = fmaf(dt[j], w4.z, a4.z);
            a4.w = fmaf(dt[j], w4.w, a4.w);
        }
        unsigned short d16[4];
        #pragma unroll
        for (int jj = 0; jj < 4; ++jj) {
            const float ac = (&a4.x)[jj];
            const float sp = (ac > 15.f) ? ac
                : 0.69314718f * log2f(1.f + exp2f(ac * 1.44269504f));
            d16[jj] = f2bf(sp);
        }
        *(bf16x4*)&delta[(size_t)grow*DD + c] = *(bf16x4*)&d16[0];
    }
}

// ---------------------------------------------------------------------------
// scan pass 1 — per-chunk local state S and delta-sum. grid B*CH, 256 thr
// Bv chunk staged in LDS (kills 4-8 VMEM loads per step -> LDS broadcast)
// ---------------------------------------------------------------------------
template<bool FAST>
__device__ __forceinline__ void scan1_impl(
    const unsigned short* __restrict__ delta,
    const unsigned short* __restrict__ xln,
    const float (*sB)[16],
    const float* al, int b, int c, int d,
    float* h, float* dsum)
{
    const int l0 = c * LC;
    for (int l = 0; l < LC; ++l) {
        const size_t base = (size_t)b*LL + l0 + l;
        const float dl = bf2f(delta[base*DD + d]);
        const float xl = bf2f(xln[base*DD + d]);
        const float dx = dl * xl;
        *dsum += dl;
        float e[NN];
        if (FAST) pow_tree(exp2f(al[0]*dl), e);
        else {
            #pragma unroll
            for (int n = 0; n < NN; ++n) e[n] = exp2f(al[n]*dl);
        }
        #pragma unroll
        for (int n = 0; n < NN; ++n)
            h[n] = fmaf(e[n], h[n], dx * sB[l][n]);
    }
}

__global__ __launch_bounds__(256) void k_scan1(
    const unsigned short* __restrict__ delta,
    const unsigned short* __restrict__ xln,
    const float* __restrict__ Bv,
    const float* __restrict__ A_log,
    float* __restrict__ S, float* __restrict__ Dsum)
{
    const int blk = blockIdx.x;
    const int c = blk & (CH-1);
    const int b = blk >> 6;
    const int d = threadIdx.x;
    __shared__ float sB[LC][16];
    if (d < 128) {
        const int l = d >> 2, q = (d & 3) * 4;
        *(float4*)&sB[l][q] = *(const float4*)&Bv[((size_t)b*LL + c*LC + l)*NN + q];
    }
    float al[NN];
    bool fast = true;
    #pragma unroll
    for (int n = 0; n < NN; ++n) {
        al[n] = -expf(A_log[d*NN + n]) * 1.44269504f;
        fast = fast && (fabsf(al[n] - (n+1)*al[0]) <= 1e-3f*fabsf(al[n]) + 1e-6f);
    }
    float h[NN];
    #pragma unroll
    for (int n = 0; n < NN; ++n) h[n] = 0.f;
    float dsum = 0.f;
    __syncthreads();
    if (fast) scan1_impl<true >(delta, xln, sB, al, b, c, d, h, &dsum);
    else      scan1_impl<false>(delta, xln, sB, al, b, c, d, h, &dsum);
    const size_t o = (size_t)blk * NN * DD + d;
    #pragma unroll
    for (int n = 0; n < NN; ++n) S[o + n*DD] = h[n];
    Dsum[(size_t)blk*DD + d] = dsum;
}

// ---------------------------------------------------------------------------
// combine: sequential fold over chunks -> per-chunk incoming state Hin
// ---------------------------------------------------------------------------
__global__ __launch_bounds__(256) void k_combine(
    const float* __restrict__ S, const float* __restrict__ Dsum,
    const float* __restrict__ A_log, float* __restrict__ Hin)
{
    const int idx = blockIdx.x * 256 + threadIdx.x;
    const int d = idx & 255;
    const int n = (idx >> 8) & 15;
    const int b = idx >> 12;
    const float al = -expf(A_log[d*NN + n]) * 1.44269504f;
    float h = 0.f;
    for (int c = 0; c < CH; ++c) {
        const size_t blk = (size_t)b*CH + c;
        const size_t o = blk*NN*DD + (size_t)n*DD + d;
        Hin[o] = h;
        h = fmaf(exp2f(al * Dsum[blk*DD + d]), h, S[o]);
    }
}

// ---------------------------------------------------------------------------
// scan pass 2 — start from Hin, full scan producing g = gelu(y)  (g aliases delta)
// ---------------------------------------------------------------------------
template<bool FAST>
__device__ __forceinline__ void scan2_impl(
    const unsigned short* __restrict__ delta,
    const unsigned short* __restrict__ xln,
    const float (*sB)[16], const float (*sC)[16],
    const float* al, int b, int c, int d,
    float* h, float dsk, unsigned short* __restrict__ g)
{
    const int l0 = c * LC;
    for (int l = 0; l < LC; ++l) {
        const size_t base = (size_t)b*LL + l0 + l;
        const float dl = bf2f(delta[base*DD + d]);
        const float xl = bf2f(xln[base*DD + d]);
        const float dx = dl * xl;
        float e[NN];
        if (FAST) pow_tree(exp2f(al[0]*dl), e);
        else {
            #pragma unroll
            for (int n = 0; n < NN; ++n) e[n] = exp2f(al[n]*dl);
        }
        float y = 0.f;
        #pragma unroll
        for (int n = 0; n < NN; ++n) {
            h[n] = fmaf(e[n], h[n], dx * sB[l][n]);
            y = fmaf(h[n], sC[l][n], y);
        }
        const float vv = y + xl * dsk;
        // gelu (tanh form)
        const float u  = 0.7978845608f * (vv + 0.044715f*vv*vv*vv);
        const float t2 = exp2f(2.8853900818f * u);
        const float th = 1.f - 2.f/(t2 + 1.f);
        g[base*DD + d] = f2bf(0.5f * vv * (1.f + th));
    }
}

__global__ __launch_bounds__(256) void k_scan2(
    const unsigned short* __restrict__ delta,
    const unsigned short* __restrict__ xln,
    const float* __restrict__ Bv,
    const float* __restrict__ Cv,
    const float* __restrict__ A_log,
    const float* __restrict__ Hin,
    const float* __restrict__ Dskip,
    unsigned short* __restrict__ g)
{
    const int blk = blockIdx.x;
    const int c = blk & (CH-1);
    const int b = blk >> 6;
    const int d = threadIdx.x;
    __shared__ float sB[LC][16], sC[LC][16];
    if (d < 128) {
        const int l = d >> 2, q = (d & 3) * 4;
        *(float4*)&sB[l][q] = *(const float4*)&Bv[((size_t)b*LL + c*LC + l)*NN + q];
    } else {
        const int dd = d - 128;
        const int l = dd >> 2, q = (dd & 3) * 4;
        *(float4*)&sC[l][q] = *(const float4*)&Cv[((size_t)b*LL + c*LC + l)*NN + q];
    }
    float al[NN];
    bool fast = true;
    #pragma unroll
    for (int n = 0; n < NN; ++n) {
        al[n] = -expf(A_log[d*NN + n]) * 1.44269504f;
        fast = fast && (fabsf(al[n] - (n+1)*al[0]) <= 1e-3f*fabsf(al[n]) + 1e-6f);
    }
    float h[NN];
    const size_t ob = (size_t)blk * NN * DD + d;
    #pragma unroll
    for (int n = 0; n < NN; ++n) h[n] = Hin[ob + n*DD];
    const float dsk = Dskip[d];
    __syncthreads();
    if (fast) scan2_impl<true >(delta, xln, sB, sC, al, b, c, d, h, dsk, g);
    else      scan2_impl<false>(delta, xln, sB, sC, al, b, c, d, h, dsk, g);
}

// ---------------------------------------------------------------------------
// GLU GEMM (32768x256 @ 256x512) + bias + sigmoid gate + skip
// ---------------------------------------------------------------------------
__global__ __launch_bounds__(256) void k_glu(
    const unsigned short* __restrict__ g,
    const unsigned short* __restrict__ Wt,
    const float* __restrict__ gb,
    const float* __restrict__ x,
    float* __restrict__ out)
{
    __shared__ unsigned short As[64][40];
    __shared__ unsigned short Bl[64][40];
    __shared__ unsigned short Bh[64][40];
    const int n0 = blockIdx.x * 64;
    const int m0 = blockIdx.y * 64;
    const int t = threadIdx.x;
    const int w = t >> 6, lane = t & 63;
    const int r = t >> 2, q = t & 3;
    const int cl = lane & 15, rq = lane >> 4;
    f32x4 accL[4], accH[4];
    const f32x4 zz = {0.f, 0.f, 0.f, 0.f};
    #pragma unroll
    for (int nf = 0; nf < 4; ++nf) { accL[nf] = zz; accH[nf] = zz; }

    for (int k0 = 0; k0 < 256; k0 += 32) {
        *(bf16x8*)(&As[r][q*8]) = *(const bf16x8*)(&g [(size_t)(m0+r)*DD + k0 + q*8]);
        *(bf16x8*)(&Bl[r][q*8]) = *(const bf16x8*)(&Wt[(size_t)(n0+r)*DD + k0 + q*8]);
        *(bf16x8*)(&Bh[r][q*8]) = *(const bf16x8*)(&Wt[(size_t)(n0+256+r)*DD + k0 + q*8]);
        __syncthreads();
        const bf16x8 a = *(const bf16x8*)(&As[w*16 + cl][rq*8]);
        #pragma unroll
        for (int nf = 0; nf < 4; ++nf) {
            const bf16x8 bl = *(const bf16x8*)(&Bl[nf*16 + cl][rq*8]);
            const bf16x8 bh = *(const bf16x8*)(&Bh[nf*16 + cl][rq*8]);
            accL[nf] = __builtin_amdgcn_mfma_f32_16x16x32_bf16(a, bl, accL[nf], 0, 0, 0);
            accH[nf] = __builtin_amdgcn_mfma_f32_16x16x32_bf16(a, bh, accH[nf], 0, 0, 0);
        }
        __syncthreads();
    }
    #pragma unroll
    for (int nf = 0; nf < 4; ++nf) {
        const int j = n0 + nf*16 + cl;
        const float bL = gb[j];
        const float bH = gb[j + 256];
        #pragma unroll
        for (int rr = 0; rr < 4; ++rr) {
            const int m = m0 + w*16 + rq*4 + rr;
            const float lo = accL[nf][rr] + bL;
            const float hi = accH[nf][rr] + bH;
            const float sg = 1.f / (1.f + exp2f(-1.44269504f * hi));
            out[(size_t)m*DD + j] = lo * sg + x[(size_t)m*DD + j];
        }
    }
}

extern "C" void kernel_launch(void* const* d_in, const int* in_sizes, int n_in,
                              void* d_out, int out_size, void* d_ws, size_t ws_size,
                              hipStream_t stream)
{
    const float* x    = (const float*)d_in[0];
    const float* ln_w = (const float*)d_in[1];
    const float* ln_b = (const float*)d_in[2];
    const float* xpw  = (const float*)d_in[3];
    const float* dtw  = (const float*)d_in[4];
    const float* dtb  = (const float*)d_in[5];
    const float* alog = (const float*)d_in[6];
    const float* dsk  = (const float*)d_in[7];
    const float* gw   = (const float*)d_in[8];
    const float* gb   = (const float*)d_in[9];
    float* out = (float*)d_out;

    char* ws = (char*)d_ws;
    size_t off = 0;
    auto alloc = [&](size_t bytes) {
        char* p = ws + off; off += (bytes + 255) & ~(size_t)255; return p;
    };
    unsigned short* xln   = (unsigned short*)alloc((size_t)BB*LL*DD*2);
    unsigned short* delta = (unsigned short*)alloc((size_t)BB*LL*DD*2);
    float*          Bvp   = (float*)         alloc((size_t)BB*LL*NN*4);
    float*          Cvp   = (float*)         alloc((size_t)BB*LL*NN*4);
    float*          S     = (float*)         alloc((size_t)BB*CH*NN*DD*4);
    float*          Dsum  = (float*)         alloc((size_t)BB*CH*DD*4);
    float*          Hin   = (float*)         alloc((size_t)BB*CH*NN*DD*4);
    unsigned short* Wt    = (unsigned short*)alloc((size_t)512*256*2);
    unsigned short* Wxt   = (unsigned short*)alloc((size_t)64*256*2);
    unsigned short* g     = delta;   // alias: scan2 overwrites delta in place

    k_prep_wx<<<16, 256, 0, stream>>>(xpw, Wxt);
    k_transpose<<<dim3(16, 8), 256, 0, stream>>>(gw, Wt);
    k_ln_fused<<<1024, 256, 0, stream>>>(x, ln_w, ln_b, Wxt, dtw, dtb, xln, delta, Bvp, Cvp);
    k_scan1<<<BB*CH, 256, 0, stream>>>(delta, xln, Bvp, alog, S, Dsum);
    k_combine<<<256, 256, 0, stream>>>(S, Dsum, alog, Hin);
    k_scan2<<<BB*CH, 256, 0, stream>>>(delta, xln, Bvp, Cvp, alog, Hin, dsk, g);
    k_glu<<<dim3(4, 512), 256, 0, stream>>>(g, Wt, gb, x, out);
}